// Round 14
// baseline (225.879 us; speedup 1.0000x reference)
//
#include <hip/hip_runtime.h>
#include <hip/hip_bf16.h>

// Problem constants
constexpr int BATCH = 8192;   // M
constexpr int THEADS = 137;   // number of predict heads (grid.y)
constexpr int DFEA = 384;     // reduction dim of GEMM1
constexpr int KHID = 128;     // per-head hidden width
constexpr float EPS_BN = 1e-5f;
constexpr float SLOPE = 0.01f;

constexpr size_t N_F  = (size_t)BATCH * DFEA;          // 3,145,728
constexpr size_t N_W1 = (size_t)THEADS * KHID * DFEA;  // 6,733,824
constexpr size_t WS_NEED = (N_F + N_W1) * sizeof(__hip_bfloat16);
constexpr int C_F8 = (int)(N_F / 8);                   // 393,216
constexpr int C_T8 = (int)((N_F + N_W1) / 8);          // 1,234,944

typedef __attribute__((ext_vector_type(8))) short bf16x8;   // 8 bf16 = 4 VGPRs
typedef __attribute__((ext_vector_type(4))) float f32x4;

__device__ __forceinline__ short cvt_bf16(float x) {
    __hip_bfloat16 b = __float2bfloat16(x);
    return *(short*)&b;
}

__device__ __forceinline__ bf16x8 load8_cvt(const float* __restrict__ g) {
    f32x4 lo = *(const f32x4*)g;
    f32x4 hi = *(const f32x4*)(g + 4);
    bf16x8 r;
    r[0] = cvt_bf16(lo[0]); r[1] = cvt_bf16(lo[1]);
    r[2] = cvt_bf16(lo[2]); r[3] = cvt_bf16(lo[3]);
    r[4] = cvt_bf16(hi[0]); r[5] = cvt_bf16(hi[1]);
    r[6] = cvt_bf16(hi[2]); r[7] = cvt_bf16(hi[3]);
    return r;
}

__device__ __forceinline__ void gload16(const void* g, void* s) {
    // async global->LDS, 16B/lane; HW dest = readfirstlane(base) + lane*16
    __builtin_amdgcn_global_load_lds((const __attribute__((address_space(1))) void*)g,
                                     (__attribute__((address_space(3))) void*)s,
                                     16, 0, 0);
}

// ---------------- pre-pass: fp32 -> bf16 bulk convert (f then W1, one launch) ----
__global__ __launch_bounds__(256) void cvt_pass(const float* __restrict__ f,
                                                const float* __restrict__ W1,
                                                __hip_bfloat16* __restrict__ ws) {
    int i = blockIdx.x * 256 + threadIdx.x;
    if (i < C_F8)
        *(bf16x8*)(ws + (size_t)i * 8) = load8_cvt(f + (size_t)i * 8);
    else if (i < C_T8)
        *(bf16x8*)(ws + (size_t)i * 8) = load8_cvt(W1 + ((size_t)i - C_F8) * 8);
}

// ---------------- main fused kernel v12: v10 sync skeleton, A global->reg -----------
// Ledger: v10 (barrier-free, A+B LDS) = 129.8us / MfmaUtil 38%; v11 tail-stage =
// 134 (null). Counter arithmetic: MFMA pipe 41%, LDS pipe ~46%, mostly SERIAL ->
// operand delivery is the wall. Of 48KB/block-step LDS reads, 16KB is A, which
// has zero inter-wave reuse -> its LDS round-trip (and 8KB/step DMA writes) is
// pure overhead. v12 = v10's 3-barrier self-paced structure with A loaded straight
// global->reg (per-lane contiguous 16B frags, L2-served; reg-double-buffered with
// ~1.5 steps slack). B stays LDS-resident per K-half (4x inter-wave reuse).
// NO manual waits in the K-loop: af (reg loads) and bfr (ds_reads) are
// compiler-score-boarded; manual vmcnt+barrier only at the 3 staging boundaries.
// LDS 81920->49152B; reads 48->32KB/block-step; writes 12->4KB/step amortized.
// v7 tested this data path at 172us but under the lockstep 2-barrier loop; its
// post-mortem blamed the sync structure -- this isolates the data path change.
__global__ __launch_bounds__(256, 2) void fused_heads_v12(
    const __hip_bfloat16* __restrict__ fb,     // [8192, 384] bf16
    const __hip_bfloat16* __restrict__ W1b,    // [137*128, 384] bf16
    const float* __restrict__ b1,
    const float* __restrict__ gmm,
    const float* __restrict__ bta,
    const float* __restrict__ rmean,
    const float* __restrict__ rvar,
    const float* __restrict__ W2,
    const float* __restrict__ b2,
    float* __restrict__ out)                   // [8192, 137]
{
    __shared__ __attribute__((aligned(16))) __hip_bfloat16 Bs[6][128 * 32];  // 48 KB

    const int tid   = threadIdx.x;
    const int lane  = tid & 63;
    const int wm    = tid >> 6;          // wave 0..3, rows wm*64..+64
    const int row16 = lane & 15;
    const int quad  = lane >> 4;
    const int m0 = blockIdx.x * 256;
    const int t  = blockIdx.y;
    const int n0 = t * KHID;

    const int swz = quad ^ ((row16 >> 1) & 3);   // v1-verified swizzled k-colblock

    // B staging (v1-verified per 128x32 tile): chunk li = tid + c*256 (c=0,1),
    // LDS bytes li*16, global row r=li>>2, colblock (li&3)^((li>>3)&3).
    const __hip_bfloat16* gB[2];
    #pragma unroll
    for (int c = 0; c < 2; ++c) {
        const int li = tid + c * 256;
        const int r = li >> 2, cb = (li & 3) ^ ((li >> 3) & 3);
        gB[c] = W1b + (size_t)(n0 + r) * DFEA + cb * 8;
    }
#define STAGEB_HALF(H)                                                        \
    { _Pragma("unroll")                                                       \
      for (int j = 0; j < 6; ++j)                                             \
          _Pragma("unroll")                                                   \
          for (int c = 0; c < 2; ++c)                                         \
              gload16(gB[c] + (H) * 192 + j * 32, &Bs[j][(tid + c * 256) * 8]); }

    // A fragment bases (v7-verified): lane reads row (wm*64 + ai*16 + row16),
    // cols quad*8..+8 -- one contiguous 16B run per lane, L2-served.
    const int laneoff = row16 * DFEA + quad * 8;
    const __hip_bfloat16* aB[4];
    #pragma unroll
    for (int ai = 0; ai < 4; ++ai)
        aB[ai] = fb + (size_t)(m0 + wm * 64 + ai * 16) * DFEA + laneoff;

#define LOADA(dst, K)                                                 \
    { _Pragma("unroll")                                               \
      for (int ai = 0; ai < 4; ++ai)                                  \
          dst[ai] = *(const bf16x8*)(aB[ai] + (K) * 32); }

    f32x4 acc[4][8];
    #pragma unroll
    for (int i = 0; i < 4; ++i)
        #pragma unroll
        for (int j = 0; j < 8; ++j)
            acc[i][j] = (f32x4){0.f, 0.f, 0.f, 0.f};

    bf16x8 afa[4], afb[4];
    // prologue: B half0 DMA (12, oldest) then af(0),af(1) reg loads (8 newest)
    STAGEB_HALF(0);
    LOADA(afa, 0);
    LOADA(afb, 1);
    asm volatile("s_waitcnt vmcnt(8)" ::: "memory");  // oldest 12 = B half0 done
    __builtin_amdgcn_s_barrier();                     // half0 visible to all waves

    // One K-step: 8 bfr ds_reads -> 32 MFMA -> reload consumed af set for KT+2.
    // No manual waits: compiler scoreboards af (vmcnt) and bfr (lgkmcnt).
    // WAR on af regs is a register dependency the scheduler must respect.
#define KSTEP(KT, AF)                                                         \
    {                                                                         \
        bf16x8 bfr[8];                                                        \
        _Pragma("unroll")                                                     \
        for (int bi = 0; bi < 8; ++bi)                                        \
            bfr[bi] = *(const bf16x8*)&Bs[(KT) % 6][(bi * 16 + row16) * 32 + swz * 8]; \
        __builtin_amdgcn_s_setprio(1);                                        \
        _Pragma("unroll")                                                     \
        for (int ai = 0; ai < 4; ++ai)                                        \
            _Pragma("unroll")                                                 \
            for (int bi = 0; bi < 8; ++bi)                                    \
                acc[ai][bi] = __builtin_amdgcn_mfma_f32_16x16x32_bf16(        \
                    AF[ai], bfr[bi], acc[ai][bi], 0, 0, 0);                   \
        __builtin_amdgcn_s_setprio(0);                                        \
        if ((KT) < 10) LOADA(AF, (KT) + 2);                                   \
    }

    KSTEP(0, afa) KSTEP(1, afb) KSTEP(2, afa) KSTEP(3, afb) KSTEP(4, afa) KSTEP(5, afb)

    // mid-kernel B re-stage: all waves done reading half0, DMA half1, drain, go.
    // (vmcnt(0) also drains af(6)/af(7) reg loads -- long returned, harmless.)
    __builtin_amdgcn_s_barrier();
    STAGEB_HALF(1);
    asm volatile("s_waitcnt vmcnt(0)" ::: "memory");
    __builtin_amdgcn_s_barrier();

    KSTEP(6, afa) KSTEP(7, afb) KSTEP(8, afa) KSTEP(9, afb) KSTEP(10, afa) KSTEP(11, afb)
#undef KSTEP
#undef LOADA
#undef STAGEB_HALF

    // ---- fused epilogue: BN (eval) + LeakyReLU + dot with W2, all in-wave ----
    float s[8], cc[8], w2v[8];
    #pragma unroll
    for (int bi = 0; bi < 8; ++bi) {
        const int n = n0 + bi * 16 + row16;
        const float sv = gmm[n] * rsqrtf(rvar[n] + EPS_BN);
        s[bi]   = sv;
        cc[bi]  = bta[n] + (b1[n] - rmean[n]) * sv;
        w2v[bi] = W2[n];
    }

    float p[4][4];
    #pragma unroll
    for (int ai = 0; ai < 4; ++ai)
        #pragma unroll
        for (int r = 0; r < 4; ++r) {
            float a = 0.f;
            #pragma unroll
            for (int bi = 0; bi < 8; ++bi) {
                float y = acc[ai][bi][r] * s[bi] + cc[bi];
                y = (y >= 0.f) ? y : SLOPE * y;   // LeakyReLU
                a += y * w2v[bi];
            }
            p[ai][r] = a;
        }

    // reduce across the 16 column-lanes (C/D: col = lane&15); masks<16 stay in-quad
    #pragma unroll
    for (int mask = 1; mask <= 8; mask <<= 1)
        #pragma unroll
        for (int ai = 0; ai < 4; ++ai)
            #pragma unroll
            for (int r = 0; r < 4; ++r)
                p[ai][r] += __shfl_xor(p[ai][r], mask);

    if (row16 == 0) {
        const float bias = b2[t];
        #pragma unroll
        for (int ai = 0; ai < 4; ++ai)
            #pragma unroll
            for (int r = 0; r < 4; ++r) {
                const int row = m0 + wm * 64 + ai * 16 + quad * 4 + r;
                out[(size_t)row * THEADS + t] = p[ai][r] + bias;
            }
    }
}

// ---------------- fallback: direct fp32 path (unchanged) ---------------------------
__global__ __launch_bounds__(256) void fused_heads_f32(
    const float* __restrict__ f, const float* __restrict__ W1,
    const float* __restrict__ b1, const float* __restrict__ gmm,
    const float* __restrict__ bta, const float* __restrict__ rmean,
    const float* __restrict__ rvar, const float* __restrict__ W2,
    const float* __restrict__ b2, float* __restrict__ out)
{
    __shared__ __attribute__((aligned(16))) __hip_bfloat16 As[128 * 32];
    __shared__ __attribute__((aligned(16))) __hip_bfloat16 Bs[128 * 32];
    __shared__ float red[2][128];

    const int tid  = threadIdx.x;
    const int lane = tid & 63;
    const int wave = tid >> 6;
    const int wmv = wave >> 1, wn = wave & 1;
    const int m0 = blockIdx.x * 128;
    const int t  = blockIdx.y;
    const int n0 = t * KHID;

    const int li0 = tid, li1 = tid + 256;
    const int r0 = li0 >> 2, c0 = (li0 & 3) * 8;
    const int r1 = li1 >> 2, c1 = (li1 & 3) * 8;
    const float* gA0 = f  + (size_t)(m0 + r0) * DFEA + c0;
    const float* gA1 = f  + (size_t)(m0 + r1) * DFEA + c1;
    const float* gB0 = W1 + (size_t)(n0 + r0) * DFEA + c0;
    const float* gB1 = W1 + (size_t)(n0 + r1) * DFEA + c1;

    const int row16 = lane & 15, quad = lane >> 4;

    f32x4 acc[4][4];
    #pragma unroll
    for (int i = 0; i < 4; ++i)
        #pragma unroll
        for (int jx = 0; jx < 4; ++jx)
            acc[i][jx] = (f32x4){0.f, 0.f, 0.f, 0.f};

    #pragma unroll 1
    for (int kt = 0; kt < DFEA / 32; ++kt) {
        const int k0 = kt * 32;
        bf16x8 va0 = load8_cvt(gA0 + k0);
        bf16x8 va1 = load8_cvt(gA1 + k0);
        bf16x8 vb0 = load8_cvt(gB0 + k0);
        bf16x8 vb1 = load8_cvt(gB1 + k0);
        __syncthreads();
        *(bf16x8*)&As[li0 * 8] = va0;
        *(bf16x8*)&As[li1 * 8] = va1;
        *(bf16x8*)&Bs[li0 * 8] = vb0;
        *(bf16x8*)&Bs[li1 * 8] = vb1;
        __syncthreads();

        bf16x8 af[4], bfr[4];
        #pragma unroll
        for (int i = 0; i < 4; ++i)
            af[i] = *(const bf16x8*)&As[(wmv * 64 + i * 16 + row16) * 32 + quad * 8];
        #pragma unroll
        for (int i = 0; i < 4; ++i)
            bfr[i] = *(const bf16x8*)&Bs[(wn * 64 + i * 16 + row16) * 32 + quad * 8];
        #pragma unroll
        for (int ai = 0; ai < 4; ++ai)
            #pragma unroll
            for (int bi = 0; bi < 4; ++bi)
                acc[ai][bi] = __builtin_amdgcn_mfma_f32_16x16x32_bf16(
                    af[ai], bfr[bi], acc[ai][bi], 0, 0, 0);
    }

    float s[4], cc[4], w2v[4];
    #pragma unroll
    for (int bi = 0; bi < 4; ++bi) {
        const int n = n0 + wn * 64 + bi * 16 + row16;
        const float sv = gmm[n] * rsqrtf(rvar[n] + EPS_BN);
        s[bi] = sv;
        cc[bi] = bta[n] + (b1[n] - rmean[n]) * sv;
        w2v[bi] = W2[n];
    }
    float p[4][4];
    #pragma unroll
    for (int ai = 0; ai < 4; ++ai)
        #pragma unroll
        for (int r = 0; r < 4; ++r) {
            float a = 0.f;
            #pragma unroll
            for (int bi = 0; bi < 4; ++bi) {
                float y = acc[ai][bi][r] * s[bi] + cc[bi];
                y = (y >= 0.f) ? y : SLOPE * y;
                a += y * w2v[bi];
            }
            p[ai][r] = a;
        }
    #pragma unroll
    for (int mask = 1; mask <= 8; mask <<= 1)
        #pragma unroll
        for (int ai = 0; ai < 4; ++ai)
            #pragma unroll
            for (int r = 0; r < 4; ++r)
                p[ai][r] += __shfl_xor(p[ai][r], mask);
    if (row16 == 0) {
        #pragma unroll
        for (int ai = 0; ai < 4; ++ai)
            #pragma unroll
            for (int r = 0; r < 4; ++r)
                red[wn][wmv * 64 + ai * 16 + quad * 4 + r] = p[ai][r];
    }
    __syncthreads();
    if (tid < 128)
        out[(size_t)(m0 + tid) * THEADS + t] = red[0][tid] + red[1][tid] + b2[t];
}

extern "C" void kernel_launch(void* const* d_in, const int* in_sizes, int n_in,
                              void* d_out, int out_size, void* d_ws, size_t ws_size,
                              hipStream_t stream) {
    (void)in_sizes; (void)n_in; (void)out_size;
    const float* f     = (const float*)d_in[0];
    const float* W1    = (const float*)d_in[1];
    const float* b1    = (const float*)d_in[2];
    const float* gmm   = (const float*)d_in[3];
    const float* bta   = (const float*)d_in[4];
    const float* rmean = (const float*)d_in[5];
    const float* rvar  = (const float*)d_in[6];
    const float* W2    = (const float*)d_in[7];
    const float* b2    = (const float*)d_in[8];
    float* out = (float*)d_out;

    if (ws_size >= WS_NEED) {
        __hip_bfloat16* fb  = (__hip_bfloat16*)d_ws;
        __hip_bfloat16* W1b = fb + N_F;
        cvt_pass<<<(C_T8 + 255) / 256, 256, 0, stream>>>(f, W1, fb);
        dim3 grid(BATCH / 256, THEADS);
        fused_heads_v12<<<grid, 256, 0, stream>>>(fb, W1b, b1, gmm, bta, rmean, rvar, W2, b2, out);
    } else {
        dim3 grid(BATCH / 128, THEADS);
        fused_heads_f32<<<grid, 256, 0, stream>>>(f, W1, b1, gmm, bta, rmean, rvar, W2, b2, out);
    }
}

// Round 15
// 206.526 us; speedup vs baseline: 1.0937x; 1.0937x over previous
//
#include <hip/hip_runtime.h>
#include <hip/hip_bf16.h>

// Problem constants
constexpr int BATCH = 8192;   // M
constexpr int THEADS = 137;   // number of predict heads (grid.y)
constexpr int DFEA = 384;     // reduction dim of GEMM1
constexpr int KHID = 128;     // per-head hidden width
constexpr float EPS_BN = 1e-5f;
constexpr float SLOPE = 0.01f;

constexpr size_t N_F  = (size_t)BATCH * DFEA;          // 3,145,728
constexpr size_t N_W1 = (size_t)THEADS * KHID * DFEA;  // 6,733,824
constexpr size_t WS_NEED = (N_F + N_W1) * sizeof(__hip_bfloat16);
constexpr int C_F8 = (int)(N_F / 8);                   // 393,216
constexpr int C_T8 = (int)((N_F + N_W1) / 8);          // 1,234,944

typedef __attribute__((ext_vector_type(8))) short bf16x8;   // 8 bf16 = 4 VGPRs
typedef __attribute__((ext_vector_type(4))) float f32x4;

__device__ __forceinline__ short cvt_bf16(float x) {
    __hip_bfloat16 b = __float2bfloat16(x);
    return *(short*)&b;
}

__device__ __forceinline__ bf16x8 load8_cvt(const float* __restrict__ g) {
    f32x4 lo = *(const f32x4*)g;
    f32x4 hi = *(const f32x4*)(g + 4);
    bf16x8 r;
    r[0] = cvt_bf16(lo[0]); r[1] = cvt_bf16(lo[1]);
    r[2] = cvt_bf16(lo[2]); r[3] = cvt_bf16(lo[3]);
    r[4] = cvt_bf16(hi[0]); r[5] = cvt_bf16(hi[1]);
    r[6] = cvt_bf16(hi[2]); r[7] = cvt_bf16(hi[3]);
    return r;
}

__device__ __forceinline__ void gload16(const void* g, void* s) {
    // async global->LDS, 16B/lane; HW dest = readfirstlane(base) + lane*16
    __builtin_amdgcn_global_load_lds((const __attribute__((address_space(1))) void*)g,
                                     (__attribute__((address_space(3))) void*)s,
                                     16, 0, 0);
}

// ---------------- pre-pass: fp32 -> bf16 bulk convert (f then W1, one launch) ----
__global__ __launch_bounds__(256) void cvt_pass(const float* __restrict__ f,
                                                const float* __restrict__ W1,
                                                __hip_bfloat16* __restrict__ ws) {
    int i = blockIdx.x * 256 + threadIdx.x;
    if (i < C_F8)
        *(bf16x8*)(ws + (size_t)i * 8) = load8_cvt(f + (size_t)i * 8);
    else if (i < C_T8)
        *(bf16x8*)(ws + (size_t)i * 8) = load8_cvt(W1 + ((size_t)i - C_F8) * 8);
}

// ---------------- main fused kernel v13: v10 + af-drain overlapped with bfr issue ---
// Ledger: v10 (A+B LDS, barrier-free self-paced) = 129.8us / MfmaUtil 38% CHAMPION;
// v11 tail-stage = 134 (lost DMA depth); v12 A-in-reg = 163 (2nd refutation of
// A-direct). v10's last exposed stall: per step, lgkmcnt(0) drained the 4 af reads
// (~120cy) while ZERO bfr reads were in flight. v13 reorders within the step:
//   af(4 ds_read) -> bfr(8 ds_read) -> lgkmcnt(8) -> sched_barrier -> STAGEA -> MFMA
// DS ops complete in-order, so lgkmcnt(8) == "oldest 4 (af) retired" -- the af
// drain overlaps the bfr issues/latency. DMA still issues BEFORE the MFMA cluster
// (keeps v10's ~1.5-step prefetch depth that v11 lost). WAR guard intact: af in
// regs before the DMA overwrites their buffer; sched_barrier stops hoisting.
// vmcnt ledger and restage block are verbatim v10.
__global__ __launch_bounds__(256, 2) void fused_heads_v13(
    const __hip_bfloat16* __restrict__ fb,     // [8192, 384] bf16
    const __hip_bfloat16* __restrict__ W1b,    // [137*128, 384] bf16
    const float* __restrict__ b1,
    const float* __restrict__ gmm,
    const float* __restrict__ bta,
    const float* __restrict__ rmean,
    const float* __restrict__ rvar,
    const float* __restrict__ W2,
    const float* __restrict__ b2,
    float* __restrict__ out)                   // [8192, 137]
{
    __shared__ __attribute__((aligned(16))) __hip_bfloat16 Bs[6][128 * 32];     // 48 KB
    __shared__ __attribute__((aligned(16))) __hip_bfloat16 As[4][2][64 * 32];   // 32 KB

    const int tid   = threadIdx.x;
    const int lane  = tid & 63;
    const int wm    = tid >> 6;          // wave 0..3, rows wm*64..+64
    const int row16 = lane & 15;
    const int quad  = lane >> 4;
    const int m0 = blockIdx.x * 256;
    const int t  = blockIdx.y;
    const int n0 = t * KHID;

    const int swz = quad ^ ((row16 >> 1) & 3);   // v1-verified swizzled k-colblock

    // B staging (v1-verified per 128x32 tile): chunk li = tid + c*256 (c=0,1),
    // LDS bytes li*16, global row r=li>>2, colblock (li&3)^((li>>3)&3).
    const __hip_bfloat16* gB[2];
    #pragma unroll
    for (int c = 0; c < 2; ++c) {
        const int li = tid + c * 256;
        const int r = li >> 2, cb = (li & 3) ^ ((li >> 3) & 3);
        gB[c] = W1b + (size_t)(n0 + r) * DFEA + cb * 8;
    }
#define STAGEB_HALF(H)                                                        \
    { _Pragma("unroll")                                                       \
      for (int j = 0; j < 6; ++j)                                             \
          _Pragma("unroll")                                                   \
          for (int c = 0; c < 2; ++c)                                         \
              gload16(gB[c] + (H) * 192 + j * 32, &Bs[j][(tid + c * 256) * 8]); }

    // A per-wave staging (v1 formula on a 64x32 tile): chunk li = lane + c*64
    // (c=0..3), r = li>>2 in [0,64), cb = (li&3)^((li>>3)&3).
    const __hip_bfloat16* gA[4];
    #pragma unroll
    for (int c = 0; c < 4; ++c) {
        const int li = lane + c * 64;
        const int r = li >> 2, cb = (li & 3) ^ ((li >> 3) & 3);
        gA[c] = fb + (size_t)(m0 + wm * 64 + r) * DFEA + cb * 8;
    }
#define STAGEA(BUF, K0)                                                       \
    { _Pragma("unroll")                                                       \
      for (int c = 0; c < 4; ++c)                                             \
          gload16(gA[c] + (K0), &As[wm][BUF][(lane + c * 64) * 8]); }

    f32x4 acc[4][8];
    #pragma unroll
    for (int i = 0; i < 4; ++i)
        #pragma unroll
        for (int j = 0; j < 8; ++j)
            acc[i][j] = (f32x4){0.f, 0.f, 0.f, 0.f};

    // prologue: B half0 (12 gloads/thread) + A(0)->buf0 + A(1)->buf1 (8/wave)
    STAGEB_HALF(0);
    STAGEA(0, 0);
    STAGEA(1, 32);
    asm volatile("s_waitcnt vmcnt(4)" ::: "memory");  // B half0 + A(0) done; A(1) in flight
    __builtin_amdgcn_s_barrier();                     // B half0 visible to all waves

    // One K-step, no barriers. A(kt) in buf kt&1; B tile Bs[kt%6].
    // af+bfr both issued, lgkmcnt(8) retires exactly the 4 af reads (in-order DS),
    // overlapping the af drain with bfr latency; then DMA A(kt+2); then MFMA
    // (compiler inserts the counted lgkm waits for bfr).
#define KSTEP(KT)                                                             \
    {                                                                         \
        if ((KT) == 11) { asm volatile("s_waitcnt vmcnt(0)" ::: "memory"); }  \
        else            { asm volatile("s_waitcnt vmcnt(4)" ::: "memory"); }  \
        bf16x8 af[4], bfr[8];                                                 \
        _Pragma("unroll")                                                     \
        for (int ai = 0; ai < 4; ++ai)                                        \
            af[ai] = *(const bf16x8*)&As[wm][(KT) & 1][(ai * 16 + row16) * 32 + swz * 8]; \
        _Pragma("unroll")                                                     \
        for (int bi = 0; bi < 8; ++bi)                                        \
            bfr[bi] = *(const bf16x8*)&Bs[(KT) % 6][(bi * 16 + row16) * 32 + swz * 8]; \
        if ((KT) < 10 && (KT) != 5) {                                         \
            asm volatile("s_waitcnt lgkmcnt(8)" ::: "memory");                \
            __builtin_amdgcn_sched_barrier(0);                                \
            STAGEA((KT) & 1, ((KT) + 2) * 32);                                \
        }                                                                     \
        __builtin_amdgcn_s_setprio(1);                                        \
        _Pragma("unroll")                                                     \
        for (int ai = 0; ai < 4; ++ai)                                        \
            _Pragma("unroll")                                                 \
            for (int bi = 0; bi < 8; ++bi)                                    \
                acc[ai][bi] = __builtin_amdgcn_mfma_f32_16x16x32_bf16(        \
                    af[ai], bfr[bi], acc[ai][bi], 0, 0, 0);                   \
        __builtin_amdgcn_s_setprio(0);                                        \
    }

    KSTEP(0) KSTEP(1) KSTEP(2) KSTEP(3) KSTEP(4) KSTEP(5)

    // mid-kernel B re-stage (verbatim v10): all waves done reading half0;
    // A(6) already in flight (issued at step 4); issue B half1 + A(7), full drain.
    __builtin_amdgcn_s_barrier();
    STAGEB_HALF(1);
    STAGEA(1, 7 * 32);
    asm volatile("s_waitcnt vmcnt(0)" ::: "memory");  // B half1 + A(6) + A(7) done
    __builtin_amdgcn_s_barrier();

    KSTEP(6) KSTEP(7) KSTEP(8) KSTEP(9) KSTEP(10) KSTEP(11)
#undef KSTEP
#undef STAGEA
#undef STAGEB_HALF

    // ---- fused epilogue: BN (eval) + LeakyReLU + dot with W2, all in-wave ----
    float s[8], cc[8], w2v[8];
    #pragma unroll
    for (int bi = 0; bi < 8; ++bi) {
        const int n = n0 + bi * 16 + row16;
        const float sv = gmm[n] * rsqrtf(rvar[n] + EPS_BN);
        s[bi]   = sv;
        cc[bi]  = bta[n] + (b1[n] - rmean[n]) * sv;
        w2v[bi] = W2[n];
    }

    float p[4][4];
    #pragma unroll
    for (int ai = 0; ai < 4; ++ai)
        #pragma unroll
        for (int r = 0; r < 4; ++r) {
            float a = 0.f;
            #pragma unroll
            for (int bi = 0; bi < 8; ++bi) {
                float y = acc[ai][bi][r] * s[bi] + cc[bi];
                y = (y >= 0.f) ? y : SLOPE * y;   // LeakyReLU
                a += y * w2v[bi];
            }
            p[ai][r] = a;
        }

    // reduce across the 16 column-lanes (C/D: col = lane&15); masks<16 stay in-quad
    #pragma unroll
    for (int mask = 1; mask <= 8; mask <<= 1)
        #pragma unroll
        for (int ai = 0; ai < 4; ++ai)
            #pragma unroll
            for (int r = 0; r < 4; ++r)
                p[ai][r] += __shfl_xor(p[ai][r], mask);

    if (row16 == 0) {
        const float bias = b2[t];
        #pragma unroll
        for (int ai = 0; ai < 4; ++ai)
            #pragma unroll
            for (int r = 0; r < 4; ++r) {
                const int row = m0 + wm * 64 + ai * 16 + quad * 4 + r;
                out[(size_t)row * THEADS + t] = p[ai][r] + bias;
            }
    }
}

// ---------------- fallback: direct fp32 path (unchanged) ---------------------------
__global__ __launch_bounds__(256) void fused_heads_f32(
    const float* __restrict__ f, const float* __restrict__ W1,
    const float* __restrict__ b1, const float* __restrict__ gmm,
    const float* __restrict__ bta, const float* __restrict__ rmean,
    const float* __restrict__ rvar, const float* __restrict__ W2,
    const float* __restrict__ b2, float* __restrict__ out)
{
    __shared__ __attribute__((aligned(16))) __hip_bfloat16 As[128 * 32];
    __shared__ __attribute__((aligned(16))) __hip_bfloat16 Bs[128 * 32];
    __shared__ float red[2][128];

    const int tid  = threadIdx.x;
    const int lane = tid & 63;
    const int wave = tid >> 6;
    const int wmv = wave >> 1, wn = wave & 1;
    const int m0 = blockIdx.x * 128;
    const int t  = blockIdx.y;
    const int n0 = t * KHID;

    const int li0 = tid, li1 = tid + 256;
    const int r0 = li0 >> 2, c0 = (li0 & 3) * 8;
    const int r1 = li1 >> 2, c1 = (li1 & 3) * 8;
    const float* gA0 = f  + (size_t)(m0 + r0) * DFEA + c0;
    const float* gA1 = f  + (size_t)(m0 + r1) * DFEA + c1;
    const float* gB0 = W1 + (size_t)(n0 + r0) * DFEA + c0;
    const float* gB1 = W1 + (size_t)(n0 + r1) * DFEA + c1;

    const int row16 = lane & 15, quad = lane >> 4;

    f32x4 acc[4][4];
    #pragma unroll
    for (int i = 0; i < 4; ++i)
        #pragma unroll
        for (int jx = 0; jx < 4; ++jx)
            acc[i][jx] = (f32x4){0.f, 0.f, 0.f, 0.f};

    #pragma unroll 1
    for (int kt = 0; kt < DFEA / 32; ++kt) {
        const int k0 = kt * 32;
        bf16x8 va0 = load8_cvt(gA0 + k0);
        bf16x8 va1 = load8_cvt(gA1 + k0);
        bf16x8 vb0 = load8_cvt(gB0 + k0);
        bf16x8 vb1 = load8_cvt(gB1 + k0);
        __syncthreads();
        *(bf16x8*)&As[li0 * 8] = va0;
        *(bf16x8*)&As[li1 * 8] = va1;
        *(bf16x8*)&Bs[li0 * 8] = vb0;
        *(bf16x8*)&Bs[li1 * 8] = vb1;
        __syncthreads();

        bf16x8 af[4], bfr[4];
        #pragma unroll
        for (int i = 0; i < 4; ++i)
            af[i] = *(const bf16x8*)&As[(wmv * 64 + i * 16 + row16) * 32 + quad * 8];
        #pragma unroll
        for (int i = 0; i < 4; ++i)
            bfr[i] = *(const bf16x8*)&Bs[(wn * 64 + i * 16 + row16) * 32 + quad * 8];
        #pragma unroll
        for (int ai = 0; ai < 4; ++ai)
            #pragma unroll
            for (int bi = 0; bi < 4; ++bi)
                acc[ai][bi] = __builtin_amdgcn_mfma_f32_16x16x32_bf16(
                    af[ai], bfr[bi], acc[ai][bi], 0, 0, 0);
    }

    float s[4], cc[4], w2v[4];
    #pragma unroll
    for (int bi = 0; bi < 4; ++bi) {
        const int n = n0 + wn * 64 + bi * 16 + row16;
        const float sv = gmm[n] * rsqrtf(rvar[n] + EPS_BN);
        s[bi] = sv;
        cc[bi] = bta[n] + (b1[n] - rmean[n]) * sv;
        w2v[bi] = W2[n];
    }
    float p[4][4];
    #pragma unroll
    for (int ai = 0; ai < 4; ++ai)
        #pragma unroll
        for (int r = 0; r < 4; ++r) {
            float a = 0.f;
            #pragma unroll
            for (int bi = 0; bi < 4; ++bi) {
                float y = acc[ai][bi][r] * s[bi] + cc[bi];
                y = (y >= 0.f) ? y : SLOPE * y;
                a += y * w2v[bi];
            }
            p[ai][r] = a;
        }
    #pragma unroll
    for (int mask = 1; mask <= 8; mask <<= 1)
        #pragma unroll
        for (int ai = 0; ai < 4; ++ai)
            #pragma unroll
            for (int r = 0; r < 4; ++r)
                p[ai][r] += __shfl_xor(p[ai][r], mask);
    if (row16 == 0) {
        #pragma unroll
        for (int ai = 0; ai < 4; ++ai)
            #pragma unroll
            for (int r = 0; r < 4; ++r)
                red[wn][wmv * 64 + ai * 16 + quad * 4 + r] = p[ai][r];
    }
    __syncthreads();
    if (tid < 128)
        out[(size_t)(m0 + tid) * THEADS + t] = red[0][tid] + red[1][tid] + b2[t];
}

extern "C" void kernel_launch(void* const* d_in, const int* in_sizes, int n_in,
                              void* d_out, int out_size, void* d_ws, size_t ws_size,
                              hipStream_t stream) {
    (void)in_sizes; (void)n_in; (void)out_size;
    const float* f     = (const float*)d_in[0];
    const float* W1    = (const float*)d_in[1];
    const float* b1    = (const float*)d_in[2];
    const float* gmm   = (const float*)d_in[3];
    const float* bta   = (const float*)d_in[4];
    const float* rmean = (const float*)d_in[5];
    const float* rvar  = (const float*)d_in[6];
    const float* W2    = (const float*)d_in[7];
    const float* b2    = (const float*)d_in[8];
    float* out = (float*)d_out;

    if (ws_size >= WS_NEED) {
        __hip_bfloat16* fb  = (__hip_bfloat16*)d_ws;
        __hip_bfloat16* W1b = fb + N_F;
        cvt_pass<<<(C_T8 + 255) / 256, 256, 0, stream>>>(f, W1, fb);
        dim3 grid(BATCH / 256, THEADS);
        fused_heads_v13<<<grid, 256, 0, stream>>>(fb, W1b, b1, gmm, bta, rmean, rvar, W2, b2, out);
    } else {
        dim3 grid(BATCH / 128, THEADS);
        fused_heads_f32<<<grid, 256, 0, stream>>>(f, W1, b1, gmm, bta, rmean, rvar, W2, b2, out);
    }
}